// Round 5
// baseline (394.170 us; speedup 1.0000x reference)
//
#include <hip/hip_runtime.h>
#include <math.h>

// ===========================================================================
// Shared epilogue: 3x3 symmetric Jacobi eigensolve (double) + output writes.
// acc layout (13 floats): [0..2]=sum f  [3..5]=sum r x f
//                         [6..11]=sum rr^T (xx,yy,zz,xy,xz,yz)  [12]=count
// ===========================================================================
__device__ __forceinline__ void frag_epilogue(
    const float* a, int f, int n_frag, const int* __restrict__ frag_sizes,
    float* __restrict__ out)
{
    float cntf  = a[12];
    float denom = fmaxf(cntf, 1.0f);
    float vfx = a[0] / denom, vfy = a[1] / denom, vfz = a[2] / denom;

    double tq0 = (double)a[3], tq1 = (double)a[4], tq2 = (double)a[5];
    double Mxx = (double)a[6], Myy = (double)a[7], Mzz = (double)a[8];
    double Mxy = (double)a[9], Mxz = (double)a[10], Myz = (double)a[11];
    double tr = Mxx + Myy + Mzz;

    double A[3][3] = {
        { tr - Mxx, -Mxy,     -Mxz     },
        { -Mxy,     tr - Myy, -Myz     },
        { -Mxz,     -Myz,     tr - Mzz }
    };
    double V[3][3] = {{1,0,0},{0,1,0},{0,0,1}};

    for (int sweep = 0; sweep < 6; ++sweep) {
        for (int pq = 0; pq < 3; ++pq) {
            int p = (pq == 2) ? 1 : 0;
            int q = (pq == 0) ? 1 : 2;
            double apq = A[p][q];
            if (fabs(apq) < 1e-300) continue;
            double theta = (A[q][q] - A[p][p]) / (2.0 * apq);
            double tt;
            if (fabs(theta) > 1e100) tt = 1.0 / (2.0 * theta);
            else tt = copysign(1.0, theta) / (fabs(theta) + sqrt(theta * theta + 1.0));
            double c = 1.0 / sqrt(tt * tt + 1.0);
            double s = tt * c;
            double app = A[p][p], aqq = A[q][q];
            A[p][p] = app - tt * apq;
            A[q][q] = aqq + tt * apq;
            A[p][q] = 0.0; A[q][p] = 0.0;
            int r = 3 - p - q;
            double arp = A[r][p], arq = A[r][q];
            A[r][p] = c * arp - s * arq; A[p][r] = A[r][p];
            A[r][q] = s * arp + c * arq; A[q][r] = A[r][q];
            for (int i2 = 0; i2 < 3; ++i2) {
                double vip = V[i2][p], viq = V[i2][q];
                V[i2][p] = c * vip - s * viq;
                V[i2][q] = s * vip + c * viq;
            }
        }
    }

    double lam0 = A[0][0], lam1 = A[1][1], lam2 = A[2][2];
    double maxeig = fmax(fmax(fmax(lam0, lam1), lam2), 1e-8);
    double thr = 0.01 * maxeig;
    bool small_frag = (frag_sizes[f] <= 1);
    double o0 = (!small_frag && lam0 > thr) ? 1.0 : 0.0;
    double o1 = (!small_frag && lam1 > thr) ? 1.0 : 0.0;
    double o2 = (!small_frag && lam2 > thr) ? 1.0 : 0.0;

    double te0 = V[0][0]*tq0 + V[1][0]*tq1 + V[2][0]*tq2;
    double te1 = V[0][1]*tq0 + V[1][1]*tq1 + V[2][1]*tq2;
    double te2 = V[0][2]*tq0 + V[1][2]*tq1 + V[2][2]*tq2;
    double we0 = te0 / fmax(lam0, 1e-6) * o0;
    double we1 = te1 / fmax(lam1, 1e-6) * o1;
    double we2 = te2 / fmax(lam2, 1e-6) * o2;
    double w0 = V[0][0]*we0 + V[0][1]*we1 + V[0][2]*we2;
    double w1 = V[1][0]*we0 + V[1][1]*we1 + V[1][2]*we2;
    double w2 = V[2][0]*we0 + V[2][1]*we1 + V[2][2]*we2;

    size_t F = (size_t)n_frag;
    out[(size_t)f*3 + 0] = vfx;
    out[(size_t)f*3 + 1] = vfy;
    out[(size_t)f*3 + 2] = vfz;
    out[F*3 + (size_t)f*3 + 0] = (float)w0;
    out[F*3 + (size_t)f*3 + 1] = (float)w1;
    out[F*3 + (size_t)f*3 + 2] = (float)w2;

    float* P = out + F*6 + (size_t)f*9;
    #pragma unroll
    for (int i2 = 0; i2 < 3; ++i2)
        #pragma unroll
        for (int k = 0; k < 3; ++k)
            P[i2*3 + k] = (float)(V[i2][0]*o0*V[k][0] + V[i2][1]*o1*V[k][1]
                                  + V[i2][2]*o2*V[k][2]);
}

// ===========================================================================
// FAST PATH (round 5): payload shrunk 32 B -> 4 B packed key (idx<<7)|lf.
// Bin: read frag_id only, scatter 4 B keys. Reduce: counting-sort keys in a
// tiny 9 KB LDS (8 blocks/CU -> 32 waves, max occupancy), parallel scan,
// then accumulate phase gathers pos/f per key (TLP hides gather latency).
// ===========================================================================
#define NB2 2048             // cursor slots (used: nbk = ceil(F/98) = 2041)
#define FPB 98               // fragments per bucket
#define CAP2 2272            // records capacity/bucket (mean 1960, sigma 44: +7σ)
#define CURSOR_STRIDE 32     // u32 per cursor: 128 B padding
#define K1_TILE 8
#define K1_APB (256 * K1_TILE)   // 2048 atoms per bin block -> 1954 blocks
#define MAXPT 9              // max records per thread in sort_reduce (ceil(CAP2/256))

__global__ __launch_bounds__(256) void init_cursors2(unsigned* __restrict__ cursors) {
    int b = blockIdx.x * 256 + threadIdx.x;
    if (b < NB2) cursors[b * CURSOR_STRIDE] = (unsigned)b * CAP2;
}

__global__ __launch_bounds__(256) void bin_atoms3(
    const int* __restrict__ frag_id,
    unsigned*  __restrict__ cursors,
    unsigned*  __restrict__ keys,
    int n_atom)
{
    __shared__ unsigned hist[NB2];
    __shared__ unsigned base[NB2];
    int t = threadIdx.x;
    for (int b = t; b < NB2; b += 256) hist[b] = 0;
    __syncthreads();

    int bs = blockIdx.x * K1_APB;
    unsigned rank[K1_TILE];
    int fidv[K1_TILE];
    #pragma unroll
    for (int j = 0; j < K1_TILE; ++j) {
        int i = bs + j * 256 + t;
        if (i < n_atom) {
            int fid = frag_id[i];
            fidv[j] = fid;
            rank[j] = atomicAdd(&hist[fid / FPB], 1u);
        } else {
            fidv[j] = -1;
        }
    }
    __syncthreads();
    for (int b = t; b < NB2; b += 256) {
        unsigned h = hist[b];
        base[b] = h ? atomicAdd(&cursors[b * CURSOR_STRIDE], h) : 0u;
    }
    __syncthreads();

    #pragma unroll
    for (int j = 0; j < K1_TILE; ++j) {
        int fid = fidv[j];
        if (fid < 0) continue;
        int i = bs + j * 256 + t;
        int bk = fid / FPB;
        unsigned pos = base[bk] + rank[j];
        if (pos >= (unsigned)(bk + 1) * CAP2) continue;   // +7σ, statistically never
        int lf = fid - bk * FPB;
        keys[pos] = ((unsigned)i << 7) | (unsigned)lf;
    }
}

__global__ __launch_bounds__(256) void sort_reduce(
    const unsigned* __restrict__ keys,
    const unsigned* __restrict__ cursors,
    const float*    __restrict__ atom_pos,
    const float*    __restrict__ f_atom,
    const float*    __restrict__ T_frag,
    const int*      __restrict__ frag_sizes,
    float*          __restrict__ out,
    int n_frag)
{
    __shared__ unsigned srt[CAP2];     // 9.1 KB sorted keys
    __shared__ unsigned hist[FPB];
    __shared__ unsigned base[128];     // scan buffer -> exclusive base

    int b = blockIdx.x, t = threadIdx.x;
    int frag0 = b * FPB;
    int nf = n_frag - frag0;
    if (nf > FPB) nf = FPB;

    for (int k = t; k < FPB; k += 256) hist[k] = 0;
    __syncthreads();

    unsigned cnt = cursors[b * CURSOR_STRIDE] - (unsigned)b * CAP2;
    if (cnt > CAP2) cnt = CAP2;
    const unsigned* kk = keys + (size_t)b * CAP2;

    // Pass A: load keys to registers, rank via 1 LDS atomic per atom.
    unsigned rkey[MAXPT], rrk[MAXPT];
    #pragma unroll
    for (int k = 0; k < MAXPT; ++k) {
        unsigned i = (unsigned)t + (unsigned)k * 256u;
        rkey[k] = 0xFFFFFFFFu;
        if (i < cnt) {
            unsigned key = kk[i];
            rkey[k] = key;
            rrk[k] = atomicAdd(&hist[key & 127u], 1u);
        }
    }
    __syncthreads();

    // Parallel inclusive scan (Hillis-Steele over 128 padded slots), 7 steps.
    if (t < 128) base[t] = (t < FPB) ? hist[t] : 0u;
    __syncthreads();
    #pragma unroll
    for (int s = 1; s < 128; s <<= 1) {
        unsigned v = 0;
        if (t < 128 && t >= s) v = base[t - s];
        __syncthreads();
        if (t < 128) base[t] += v;
        __syncthreads();
    }
    if (t < FPB) base[t] -= hist[t];   // exclusive
    __syncthreads();

    // Pass B: scatter keys into sorted LDS positions (no atomics).
    #pragma unroll
    for (int k = 0; k < MAXPT; ++k) {
        unsigned key = rkey[k];
        if (key != 0xFFFFFFFFu)
            srt[base[key & 127u] + rrk[k]] = key;
    }
    __syncthreads();

    // Accumulate: 2 lanes/fragment walk contiguous sorted keys, gather pos/f.
    if (t < 2 * nf) {
        int g = t >> 1, h = t & 1;
        int f = frag0 + g;
        float Tx = T_frag[3*f+0], Ty = T_frag[3*f+1], Tz = T_frag[3*f+2];
        float s[13];
        #pragma unroll
        for (int k = 0; k < 13; ++k) s[k] = 0.0f;
        unsigned b0 = base[g], c = hist[g];
        for (unsigned k = b0 + h; k < b0 + c; k += 2) {
            unsigned idx = srt[k] >> 7;
            const float* pp = atom_pos + 3 * (size_t)idx;
            const float* ff = f_atom  + 3 * (size_t)idx;
            float rx = pp[0] - Tx, ry = pp[1] - Ty, rz = pp[2] - Tz;
            float Fx = ff[0], Fy = ff[1], Fz = ff[2];
            s[0] += Fx; s[1] += Fy; s[2] += Fz;
            s[3] += ry*Fz - rz*Fy;
            s[4] += rz*Fx - rx*Fz;
            s[5] += rx*Fy - ry*Fx;
            s[6] += rx*rx; s[7] += ry*ry; s[8] += rz*rz;
            s[9] += rx*ry; s[10] += rx*rz; s[11] += ry*rz;
        }
        #pragma unroll
        for (int k = 0; k < 12; ++k) s[k] += __shfl_xor(s[k], 1);
        if (h == 0) {
            s[12] = (float)c;
            frag_epilogue(s, f, n_frag, frag_sizes, out);
        }
    }
}

// ===========================================================================
// FALLBACK: direct global f32 atomics (round-1, correctness-safe, any ws)
// ===========================================================================
#define NACC 16

__global__ __launch_bounds__(256) void atom_scatter_fb(
    const float* __restrict__ f_atom, const float* __restrict__ atom_pos,
    const float* __restrict__ T_frag, const int* __restrict__ frag_id,
    float* __restrict__ acc, int n_atom)
{
    int i = blockIdx.x * blockDim.x + threadIdx.x;
    if (i >= n_atom) return;
    int fid = frag_id[i];
    float fx = f_atom[3*i+0], fy = f_atom[3*i+1], fz = f_atom[3*i+2];
    float px = atom_pos[3*i+0], py = atom_pos[3*i+1], pz = atom_pos[3*i+2];
    float rx = px - T_frag[3*fid+0], ry = py - T_frag[3*fid+1], rz = pz - T_frag[3*fid+2];
    float cx = ry*fz - rz*fy, cy = rz*fx - rx*fz, cz = rx*fy - ry*fx;
    float* a = acc + (size_t)fid * NACC;
    atomicAdd(a+0, fx);    atomicAdd(a+1, fy);    atomicAdd(a+2, fz);
    atomicAdd(a+3, cx);    atomicAdd(a+4, cy);    atomicAdd(a+5, cz);
    atomicAdd(a+6, rx*rx); atomicAdd(a+7, ry*ry); atomicAdd(a+8, rz*rz);
    atomicAdd(a+9, rx*ry); atomicAdd(a+10, rx*rz); atomicAdd(a+11, ry*rz);
    atomicAdd(a+12, 1.0f);
}

__global__ __launch_bounds__(256) void frag_solve_fb(
    const float* __restrict__ acc, const int* __restrict__ frag_sizes,
    float* __restrict__ out, int n_frag)
{
    int f = blockIdx.x * blockDim.x + threadIdx.x;
    if (f >= n_frag) return;
    float a[13];
    #pragma unroll
    for (int k = 0; k < 13; ++k) a[k] = acc[(size_t)f * NACC + k];
    frag_epilogue(a, f, n_frag, frag_sizes, out);
}

extern "C" void kernel_launch(void* const* d_in, const int* in_sizes, int n_in,
                              void* d_out, int out_size, void* d_ws, size_t ws_size,
                              hipStream_t stream) {
    const float* f_atom     = (const float*)d_in[0];
    const float* atom_pos   = (const float*)d_in[1];
    const float* T_frag     = (const float*)d_in[2];
    const int*   frag_id    = (const int*)d_in[3];
    const int*   frag_sizes = (const int*)d_in[4];
    int n_atom = in_sizes[0] / 3;
    int n_frag = in_sizes[2] / 3;
    float* out = (float*)d_out;

    size_t cursors_bytes = (size_t)NB2 * CURSOR_STRIDE * sizeof(unsigned);   // 256 KB
    size_t keys_bytes    = (size_t)NB2 * CAP2 * sizeof(unsigned);            // ~18.6 MB
    size_t need = cursors_bytes + keys_bytes;
    int nbk = (n_frag + FPB - 1) / FPB;   // 2041 buckets used

    // Packed key needs idx in 25 bits (idx<<7): n_atom < 2^25 = 33.5M
    if (ws_size >= need && nbk <= NB2 && n_atom < (1 << 25)) {
        unsigned* cursors = (unsigned*)d_ws;
        unsigned* keyarr  = (unsigned*)((char*)d_ws + cursors_bytes);

        init_cursors2<<<(NB2 + 255) / 256, 256, 0, stream>>>(cursors);
        int bin_blocks = (n_atom + K1_APB - 1) / K1_APB;
        bin_atoms3<<<bin_blocks, 256, 0, stream>>>(frag_id, cursors, keyarr, n_atom);
        sort_reduce<<<nbk, 256, 0, stream>>>(
            keyarr, cursors, atom_pos, f_atom, T_frag, frag_sizes, out, n_frag);
    } else {
        float* acc = (float*)d_ws;
        hipMemsetAsync(acc, 0, (size_t)n_frag * NACC * sizeof(float), stream);
        atom_scatter_fb<<<(n_atom + 255) / 256, 256, 0, stream>>>(
            f_atom, atom_pos, T_frag, frag_id, acc, n_atom);
        frag_solve_fb<<<(n_frag + 255) / 256, 256, 0, stream>>>(acc, frag_sizes, out, n_frag);
    }
}

// Round 6
// 389.960 us; speedup vs baseline: 1.0108x; 1.0108x over previous
//
#include <hip/hip_runtime.h>
#include <math.h>

// ===========================================================================
// Shared epilogue: 3x3 symmetric Jacobi eigensolve (double) + output writes.
// acc layout (13 floats): [0..2]=sum f  [3..5]=sum r x f
//                         [6..11]=sum rr^T (xx,yy,zz,xy,xz,yz)  [12]=count
// ===========================================================================
__device__ __forceinline__ void frag_epilogue(
    const float* a, int f, int n_frag, const int* __restrict__ frag_sizes,
    float* __restrict__ out)
{
    float cntf  = a[12];
    float denom = fmaxf(cntf, 1.0f);
    float vfx = a[0] / denom, vfy = a[1] / denom, vfz = a[2] / denom;

    double tq0 = (double)a[3], tq1 = (double)a[4], tq2 = (double)a[5];
    double Mxx = (double)a[6], Myy = (double)a[7], Mzz = (double)a[8];
    double Mxy = (double)a[9], Mxz = (double)a[10], Myz = (double)a[11];
    double tr = Mxx + Myy + Mzz;

    double A[3][3] = {
        { tr - Mxx, -Mxy,     -Mxz     },
        { -Mxy,     tr - Myy, -Myz     },
        { -Mxz,     -Myz,     tr - Mzz }
    };
    double V[3][3] = {{1,0,0},{0,1,0},{0,0,1}};

    for (int sweep = 0; sweep < 6; ++sweep) {
        for (int pq = 0; pq < 3; ++pq) {
            int p = (pq == 2) ? 1 : 0;
            int q = (pq == 0) ? 1 : 2;
            double apq = A[p][q];
            // relative early-out: converged rotations cost ~nothing
            if (fabs(apq) <= 1e-14 * (fabs(A[p][p]) + fabs(A[q][q])) ||
                fabs(apq) < 1e-300) continue;
            double theta = (A[q][q] - A[p][p]) / (2.0 * apq);
            double tt;
            if (fabs(theta) > 1e100) tt = 1.0 / (2.0 * theta);
            else tt = copysign(1.0, theta) / (fabs(theta) + sqrt(theta * theta + 1.0));
            double c = 1.0 / sqrt(tt * tt + 1.0);
            double s = tt * c;
            double app = A[p][p], aqq = A[q][q];
            A[p][p] = app - tt * apq;
            A[q][q] = aqq + tt * apq;
            A[p][q] = 0.0; A[q][p] = 0.0;
            int r = 3 - p - q;
            double arp = A[r][p], arq = A[r][q];
            A[r][p] = c * arp - s * arq; A[p][r] = A[r][p];
            A[r][q] = s * arp + c * arq; A[q][r] = A[r][q];
            for (int i2 = 0; i2 < 3; ++i2) {
                double vip = V[i2][p], viq = V[i2][q];
                V[i2][p] = c * vip - s * viq;
                V[i2][q] = s * vip + c * viq;
            }
        }
    }

    double lam0 = A[0][0], lam1 = A[1][1], lam2 = A[2][2];
    double maxeig = fmax(fmax(fmax(lam0, lam1), lam2), 1e-8);
    double thr = 0.01 * maxeig;
    bool small_frag = (frag_sizes[f] <= 1);
    double o0 = (!small_frag && lam0 > thr) ? 1.0 : 0.0;
    double o1 = (!small_frag && lam1 > thr) ? 1.0 : 0.0;
    double o2 = (!small_frag && lam2 > thr) ? 1.0 : 0.0;

    double te0 = V[0][0]*tq0 + V[1][0]*tq1 + V[2][0]*tq2;
    double te1 = V[0][1]*tq0 + V[1][1]*tq1 + V[2][1]*tq2;
    double te2 = V[0][2]*tq0 + V[1][2]*tq1 + V[2][2]*tq2;
    double we0 = te0 / fmax(lam0, 1e-6) * o0;
    double we1 = te1 / fmax(lam1, 1e-6) * o1;
    double we2 = te2 / fmax(lam2, 1e-6) * o2;
    double w0 = V[0][0]*we0 + V[0][1]*we1 + V[0][2]*we2;
    double w1 = V[1][0]*we0 + V[1][1]*we1 + V[1][2]*we2;
    double w2 = V[2][0]*we0 + V[2][1]*we1 + V[2][2]*we2;

    size_t F = (size_t)n_frag;
    out[(size_t)f*3 + 0] = vfx;
    out[(size_t)f*3 + 1] = vfy;
    out[(size_t)f*3 + 2] = vfz;
    out[F*3 + (size_t)f*3 + 0] = (float)w0;
    out[F*3 + (size_t)f*3 + 1] = (float)w1;
    out[F*3 + (size_t)f*3 + 2] = (float)w2;

    float* P = out + F*6 + (size_t)f*9;
    #pragma unroll
    for (int i2 = 0; i2 < 3; ++i2)
        #pragma unroll
        for (int k = 0; k < 3; ++k)
            P[i2*3 + k] = (float)(V[i2][0]*o0*V[k][0] + V[i2][1]*o1*V[k][1]
                                  + V[i2][2]*o2*V[k][2]);
}

// ===========================================================================
// FAST PATH (round 6): round-4 bin (32 B records, no gather downstream) +
// sort_reduce WITHOUT the f64 epilogue (writes 13 sums/frag into its own
// consumed recs region) + dense frag_eig kernel (every lane solves one 3x3).
// ===========================================================================
#define NB2 2048             // buckets (used: nbk = ceil(F/98) = 2041)
#define FPB 98               // fragments per bucket
#define CAP2 2272            // records capacity/bucket (mean 1960, sigma 44: +7σ)
#define CURSOR_STRIDE 32     // u32 per cursor: 128 B padding
#define K1_TILE 32
#define K1_APB (256 * K1_TILE)   // 8192 atoms per bin block
#define MAXPT 9              // ceil(CAP2/256)

__global__ __launch_bounds__(256) void init_cursors2(unsigned* __restrict__ cursors) {
    int b = blockIdx.x * 256 + threadIdx.x;
    if (b < NB2) cursors[b * CURSOR_STRIDE] = (unsigned)b * CAP2;
}

__global__ __launch_bounds__(256) void bin_atoms2(
    const float* __restrict__ f_atom,
    const float* __restrict__ atom_pos,
    const int*   __restrict__ frag_id,
    unsigned*    __restrict__ cursors,
    float4*      __restrict__ recs,
    int n_atom)
{
    __shared__ unsigned hist[NB2];
    __shared__ unsigned base[NB2];
    int t = threadIdx.x;
    for (int b = t; b < NB2; b += 256) hist[b] = 0;
    __syncthreads();

    int bs = blockIdx.x * K1_APB;
    unsigned rank[K1_TILE];
    int fidv[K1_TILE];
    #pragma unroll
    for (int j = 0; j < K1_TILE; ++j) {
        int i = bs + j * 256 + t;
        if (i < n_atom) {
            int fid = frag_id[i];
            fidv[j] = fid;
            rank[j] = atomicAdd(&hist[fid / FPB], 1u);
        } else {
            fidv[j] = -1;
        }
    }
    __syncthreads();
    for (int b = t; b < NB2; b += 256) {
        unsigned h = hist[b];
        base[b] = h ? atomicAdd(&cursors[b * CURSOR_STRIDE], h) : 0u;
    }
    __syncthreads();

    #pragma unroll
    for (int j = 0; j < K1_TILE; ++j) {
        int fid = fidv[j];
        if (fid < 0) continue;
        int i = bs + j * 256 + t;
        int bk = fid / FPB;
        unsigned pos = base[bk] + rank[j];
        if (pos >= (unsigned)(bk + 1) * CAP2) continue;   // +7σ, statistically never
        float px = atom_pos[3*i+0], py = atom_pos[3*i+1], pz = atom_pos[3*i+2];
        float fx = f_atom[3*i+0],  fy = f_atom[3*i+1],  fz = f_atom[3*i+2];
        int lf = fid - bk * FPB;
        recs[2*(size_t)pos + 0] = make_float4(px, py, pz, __int_as_float(lf));
        recs[2*(size_t)pos + 1] = make_float4(fx, fy, fz, 0.0f);
    }
}

// Counting-sort records in LDS, accumulate 13 sums/frag, store sums into the
// (fully consumed) head of this bucket's recs region as SoA [13][FPB].
__global__ __launch_bounds__(256) void sort_reduce(
    float4*         __restrict__ recs,
    const unsigned* __restrict__ cursors,
    const float*    __restrict__ T_frag,
    int n_frag)
{
    __shared__ float    srt[CAP2 * 8];   // 72.7 KB: 2 x float4 per record
    __shared__ unsigned hist[FPB];
    __shared__ unsigned base[128];

    int b = blockIdx.x, t = threadIdx.x;
    int frag0 = b * FPB;
    int nf = n_frag - frag0;
    if (nf > FPB) nf = FPB;

    for (int k = t; k < FPB; k += 256) hist[k] = 0;
    __syncthreads();

    unsigned cnt = cursors[b * CURSOR_STRIDE] - (unsigned)b * CAP2;
    if (cnt > CAP2) cnt = CAP2;
    float4* rec = recs + 2 * (size_t)b * CAP2;

    // Pass A: load records to registers, rank via 1 LDS atomic per atom.
    float4 rv[MAXPT], fv[MAXPT];
    int rlf[MAXPT];
    unsigned rrk[MAXPT];
    #pragma unroll
    for (int k = 0; k < MAXPT; ++k) {
        unsigned i = (unsigned)t + (unsigned)k * 256u;
        rlf[k] = -1;
        if (i < cnt) {
            rv[k] = rec[2*i + 0];
            fv[k] = rec[2*i + 1];
            int lf = __float_as_int(rv[k].w);
            rlf[k] = lf;
            rrk[k] = atomicAdd(&hist[lf], 1u);
        }
    }
    __syncthreads();

    // Parallel inclusive scan (Hillis-Steele over 128 slots) -> exclusive base.
    if (t < 128) base[t] = (t < FPB) ? hist[t] : 0u;
    __syncthreads();
    #pragma unroll
    for (int s = 1; s < 128; s <<= 1) {
        unsigned v = 0;
        if (t < 128 && t >= s) v = base[t - s];
        __syncthreads();
        if (t < 128) base[t] += v;
        __syncthreads();
    }
    if (t < FPB) base[t] -= hist[t];
    __syncthreads();

    // Pass B: scatter records into sorted LDS slots (2 x b128 each).
    #pragma unroll
    for (int k = 0; k < MAXPT; ++k) {
        if (rlf[k] >= 0) {
            unsigned p = base[rlf[k]] + rrk[k];
            float4* d = (float4*)&srt[p * 8];
            d[0] = rv[k];
            d[1] = fv[k];
        }
    }
    __syncthreads();

    // Accumulate: 2 lanes/fragment walk contiguous sorted records.
    if (t < 2 * nf) {
        int g = t >> 1, h = t & 1;
        int f = frag0 + g;
        float Tx = T_frag[3*f+0], Ty = T_frag[3*f+1], Tz = T_frag[3*f+2];
        float s[12];
        #pragma unroll
        for (int k = 0; k < 12; ++k) s[k] = 0.0f;
        unsigned b0 = base[g], c = hist[g];
        for (unsigned k = b0 + h; k < b0 + c; k += 2) {
            float4 a0 = *(float4*)&srt[k * 8];
            float4 a1 = *(float4*)&srt[k * 8 + 4];
            float rx = a0.x - Tx, ry = a0.y - Ty, rz = a0.z - Tz;
            float Fx = a1.x, Fy = a1.y, Fz = a1.z;
            s[0] += Fx; s[1] += Fy; s[2] += Fz;
            s[3] += ry*Fz - rz*Fy;
            s[4] += rz*Fx - rx*Fz;
            s[5] += rx*Fy - ry*Fx;
            s[6] += rx*rx; s[7] += ry*ry; s[8] += rz*rz;
            s[9] += rx*ry; s[10] += rx*rz; s[11] += ry*rz;
        }
        #pragma unroll
        for (int k = 0; k < 12; ++k) s[k] += __shfl_xor(s[k], 1);
        if (h == 0) {
            // Store sums SoA into this bucket's own recs region (fully read).
            float* accR = (float*)rec;
            #pragma unroll
            for (int k = 0; k < 12; ++k) accR[k * FPB + g] = s[k];
            accR[12 * FPB + g] = (float)c;
        }
    }
}

// Dense eigensolve: one fragment per lane, all 64 lanes busy.
__global__ __launch_bounds__(256) void frag_eig(
    const float4* __restrict__ recs,
    const int*    __restrict__ frag_sizes,
    float*        __restrict__ out,
    int n_frag)
{
    int f = blockIdx.x * 256 + threadIdx.x;
    if (f >= n_frag) return;
    int b  = f / FPB;
    int lf = f - b * FPB;
    const float* accR = (const float*)(recs + 2 * (size_t)b * CAP2);
    float a[13];
    #pragma unroll
    for (int k = 0; k < 13; ++k) a[k] = accR[k * FPB + lf];
    frag_epilogue(a, f, n_frag, frag_sizes, out);
}

// ===========================================================================
// FALLBACK: direct global f32 atomics (round-1, correctness-safe, any ws)
// ===========================================================================
#define NACC 16

__global__ __launch_bounds__(256) void atom_scatter_fb(
    const float* __restrict__ f_atom, const float* __restrict__ atom_pos,
    const float* __restrict__ T_frag, const int* __restrict__ frag_id,
    float* __restrict__ acc, int n_atom)
{
    int i = blockIdx.x * blockDim.x + threadIdx.x;
    if (i >= n_atom) return;
    int fid = frag_id[i];
    float fx = f_atom[3*i+0], fy = f_atom[3*i+1], fz = f_atom[3*i+2];
    float px = atom_pos[3*i+0], py = atom_pos[3*i+1], pz = atom_pos[3*i+2];
    float rx = px - T_frag[3*fid+0], ry = py - T_frag[3*fid+1], rz = pz - T_frag[3*fid+2];
    float cx = ry*fz - rz*fy, cy = rz*fx - rx*fz, cz = rx*fy - ry*fx;
    float* a = acc + (size_t)fid * NACC;
    atomicAdd(a+0, fx);    atomicAdd(a+1, fy);    atomicAdd(a+2, fz);
    atomicAdd(a+3, cx);    atomicAdd(a+4, cy);    atomicAdd(a+5, cz);
    atomicAdd(a+6, rx*rx); atomicAdd(a+7, ry*ry); atomicAdd(a+8, rz*rz);
    atomicAdd(a+9, rx*ry); atomicAdd(a+10, rx*rz); atomicAdd(a+11, ry*rz);
    atomicAdd(a+12, 1.0f);
}

__global__ __launch_bounds__(256) void frag_solve_fb(
    const float* __restrict__ acc, const int* __restrict__ frag_sizes,
    float* __restrict__ out, int n_frag)
{
    int f = blockIdx.x * blockDim.x + threadIdx.x;
    if (f >= n_frag) return;
    float a[13];
    #pragma unroll
    for (int k = 0; k < 13; ++k) a[k] = acc[(size_t)f * NACC + k];
    frag_epilogue(a, f, n_frag, frag_sizes, out);
}

extern "C" void kernel_launch(void* const* d_in, const int* in_sizes, int n_in,
                              void* d_out, int out_size, void* d_ws, size_t ws_size,
                              hipStream_t stream) {
    const float* f_atom     = (const float*)d_in[0];
    const float* atom_pos   = (const float*)d_in[1];
    const float* T_frag     = (const float*)d_in[2];
    const int*   frag_id    = (const int*)d_in[3];
    const int*   frag_sizes = (const int*)d_in[4];
    int n_atom = in_sizes[0] / 3;
    int n_frag = in_sizes[2] / 3;
    float* out = (float*)d_out;

    size_t cursors_bytes = (size_t)NB2 * CURSOR_STRIDE * sizeof(unsigned);   // 256 KB
    size_t recs_bytes    = (size_t)NB2 * CAP2 * 2 * sizeof(float4);          // ~148.9 MB
    size_t need = cursors_bytes + recs_bytes;
    int nbk = (n_frag + FPB - 1) / FPB;   // 2041 buckets used

    if (ws_size >= need && nbk <= NB2) {
        unsigned* cursors = (unsigned*)d_ws;
        float4* recs = (float4*)((char*)d_ws + cursors_bytes);

        init_cursors2<<<(NB2 + 255) / 256, 256, 0, stream>>>(cursors);
        int bin_blocks = (n_atom + K1_APB - 1) / K1_APB;
        bin_atoms2<<<bin_blocks, 256, 0, stream>>>(
            f_atom, atom_pos, frag_id, cursors, recs, n_atom);
        sort_reduce<<<nbk, 256, 0, stream>>>(recs, cursors, T_frag, n_frag);
        frag_eig<<<(n_frag + 255) / 256, 256, 0, stream>>>(
            recs, frag_sizes, out, n_frag);
    } else {
        float* acc = (float*)d_ws;
        hipMemsetAsync(acc, 0, (size_t)n_frag * NACC * sizeof(float), stream);
        atom_scatter_fb<<<(n_atom + 255) / 256, 256, 0, stream>>>(
            f_atom, atom_pos, T_frag, frag_id, acc, n_atom);
        frag_solve_fb<<<(n_frag + 255) / 256, 256, 0, stream>>>(acc, frag_sizes, out, n_frag);
    }
}